// Round 6
// baseline (391.751 us; speedup 1.0000x reference)
//
#include <hip/hip_runtime.h>
#include <hip/hip_bf16.h>

// BilinearPooling: out[b, i*2048+j] = xp[b,i]*yp[b,j] / max(||xp_b||*||yp_b||, eps)
// where xp = x @ W^T, yp = y @ W^T.  B=32, D_IN=1024, D_OUT=2048, fp32.
// ||outer(u,v)||_F = ||u||*||v||  ->  never materialize z before normalizing.
//
// R5 status: three good write patterns all ~110.5us; 8MiB-stride row-thrash 137us.
// DIAGNOSTIC ROUND: writer does 4 identical streaming passes (1 real -> d_out,
// 3 -> disjoint 512MB d_ws streams) so the writer dispatch writes the same
// 2 GiB as the harness fill and enters the rocprof top-5 -> read its true BW.
// Output is bit-identical to R5 (pass 0 unchanged). W = (dur - 110.6)/3.

#define BROWS 64       // stacked rows: 32 x-rows then 32 y-rows
#define DIN   1024
#define DOUT  2048
#define OTILE 64
#define LDA   132      // padded LDS leading dim (floats)
#define EPS_N 1e-12f

// ---------------- Kernel 1: partial GEMM  proj_partial[ks][r][o] ----------------
template <int KS>
__global__ __launch_bounds__(256) void gemm_partial_k(
    const float* __restrict__ x, const float* __restrict__ y,
    const float* __restrict__ W, float* __restrict__ part)
{
    constexpr int KCHUNK = DIN / KS;
    constexpr int NSTAGE = KCHUNK / 128;

    const int o0 = blockIdx.x * OTILE;
    const int ks = blockIdx.y;
    const int t  = threadIdx.x;

    __shared__ float As[BROWS * LDA];
    __shared__ float Bs[OTILE * LDA];

    const int tr = t >> 4;
    const int tc = t & 15;

    float acc[4][4];
#pragma unroll
    for (int a = 0; a < 4; ++a)
#pragma unroll
        for (int b = 0; b < 4; ++b) acc[a][b] = 0.f;

    for (int st = 0; st < NSTAGE; ++st) {
        const int k0 = ks * KCHUNK + st * 128;
        if (st) __syncthreads();
#pragma unroll
        for (int i = 0; i < 8; ++i) {
            int li = t + i * 256;
            int r  = li >> 5;
            int c4 = li & 31;
            const float* src =
                (r < 32 ? x + (size_t)r * DIN : y + (size_t)(r - 32) * DIN)
                + k0 + c4 * 4;
            *(float4*)&As[r * LDA + c4 * 4] = *(const float4*)src;
        }
#pragma unroll
        for (int i = 0; i < 8; ++i) {
            int li = t + i * 256;
            int r  = li >> 5;
            int c4 = li & 31;
            *(float4*)&Bs[r * LDA + c4 * 4] =
                *(const float4*)(W + (size_t)(o0 + r) * DIN + k0 + c4 * 4);
        }
        __syncthreads();

#pragma unroll 8
        for (int k4 = 0; k4 < 32; ++k4) {
            const int k = k4 * 4;
            float4 av[4], bv[4];
#pragma unroll
            for (int rr = 0; rr < 4; ++rr)
                av[rr] = *(float4*)&As[(tr + 16 * rr) * LDA + k];
#pragma unroll
            for (int cc = 0; cc < 4; ++cc)
                bv[cc] = *(float4*)&Bs[(tc + 16 * cc) * LDA + k];
#pragma unroll
            for (int rr = 0; rr < 4; ++rr)
#pragma unroll
                for (int cc = 0; cc < 4; ++cc) {
                    acc[rr][cc] = fmaf(av[rr].x, bv[cc].x, acc[rr][cc]);
                    acc[rr][cc] = fmaf(av[rr].y, bv[cc].y, acc[rr][cc]);
                    acc[rr][cc] = fmaf(av[rr].z, bv[cc].z, acc[rr][cc]);
                    acc[rr][cc] = fmaf(av[rr].w, bv[cc].w, acc[rr][cc]);
                }
        }
    }

#pragma unroll
    for (int rr = 0; rr < 4; ++rr) {
        const int r = tr + 16 * rr;
#pragma unroll
        for (int cc = 0; cc < 4; ++cc) {
            const int o = o0 + tc + 16 * cc;
            part[((size_t)(ks * BROWS + r)) * DOUT + o] = acc[rr][cc];
        }
    }
}

// ---------------- Kernel 2: reduce partials + row norms ----------------
template <int KS>
__global__ __launch_bounds__(256) void reduce_rows_k(
    const float* __restrict__ part, float* __restrict__ proj,
    float* __restrict__ norms)
{
    const int r = blockIdx.x;
    const int t = threadIdx.x;
    float ss = 0.f;
#pragma unroll
    for (int it = 0; it < 2; ++it) {
        const int j4 = t + it * 256;
        float4 s = make_float4(0.f, 0.f, 0.f, 0.f);
#pragma unroll
        for (int ks = 0; ks < KS; ++ks) {
            float4 v = *(const float4*)&part[((size_t)(ks * BROWS + r)) * DOUT + j4 * 4];
            s.x += v.x; s.y += v.y; s.z += v.z; s.w += v.w;
        }
        *(float4*)&proj[(size_t)r * DOUT + j4 * 4] = s;
        ss += s.x * s.x + s.y * s.y + s.z * s.z + s.w * s.w;
    }
#pragma unroll
    for (int m = 32; m >= 1; m >>= 1) ss += __shfl_xor(ss, m, 64);
    __shared__ float red[4];
    const int lane = t & 63, wv = t >> 6;
    if (lane == 0) red[wv] = ss;
    __syncthreads();
    if (t == 0) norms[r] = sqrtf(red[0] + red[1] + red[2] + red[3]);
}

// ---------------- Kernel 3: per-wave-sequential streaming write ----------------
// v3 pattern (R5, 110.6us): block = (b, 32 rows); wave w owns 8 consecutive rows
// = contiguous 64KB sequential run. NPASS=4: pass 0 -> out (real result),
// passes 1..3 -> disjoint 512MB ws streams, identical pattern.
template <int NPASS>
__global__ __launch_bounds__(256) void outer_write_v3(
    const float* __restrict__ proj, const float* __restrict__ norms,
    float* __restrict__ out,
    float* __restrict__ ws1, float* __restrict__ ws2, float* __restrict__ ws3)
{
    const int blk = blockIdx.x;        // 0..2047
    const int b   = blk >> 6;          // 0..31
    const int i0  = (blk & 63) << 5;   // row tile of 32
    const int t   = threadIdx.x;
    const int w   = t >> 6;            // wave 0..3
    const int l   = t & 63;

    const float s = 1.0f / fmaxf(norms[b] * norms[32 + b], EPS_N);

    const float* yrow = proj + (size_t)(32 + b) * DOUT;
    float4 y4[8];
#pragma unroll
    for (int sseg = 0; sseg < 8; ++sseg) {
        float4 v = *(const float4*)&yrow[sseg * 256 + l * 4];
        y4[sseg] = make_float4(v.x * s, v.y * s, v.z * s, v.w * s);
    }

    const float* xrow = proj + (size_t)b * DOUT + i0 + w * 8;
    const size_t slice = ((size_t)b * DOUT + i0 + w * 8) * (DOUT / 4) + l;

    float* const bases[4] = { out, ws1, ws2, ws3 };

#pragma unroll
    for (int p = 0; p < NPASS; ++p) {
        float4* outp = (float4*)bases[p] + slice;
#pragma unroll
        for (int r = 0; r < 8; ++r) {
            const float xv = xrow[r];
#pragma unroll
            for (int sseg = 0; sseg < 8; ++sseg) {
                float4 o = make_float4(xv * y4[sseg].x, xv * y4[sseg].y,
                                       xv * y4[sseg].z, xv * y4[sseg].w);
                outp[(size_t)r * (DOUT / 4) + sseg * 64] = o;
            }
        }
    }
}

// ---------------- launch ----------------
#define FE_FLOATS   ((size_t)4 * 1024 * 1024)              // 16MB region for FE scratch
#define STREAM_FLOATS ((size_t)(512 + 2) * 1024 * 1024 / 4) // 512MB stream + 2MB skew

template <int KS>
static void run_pipeline(const float* x, const float* y, const float* W,
                         float* out, float* ws, size_t ws_size, hipStream_t stream)
{
    float* part  = ws;
    float* proj  = part + (size_t)KS * BROWS * DOUT;
    float* norms = proj + (size_t)BROWS * DOUT;
    gemm_partial_k<KS><<<dim3(DOUT / OTILE, KS), 256, 0, stream>>>(x, y, W, part);
    reduce_rows_k<KS><<<BROWS, 256, 0, stream>>>(part, proj, norms);

    const size_t diag_need = (FE_FLOATS + 3 * STREAM_FLOATS) * sizeof(float);
    if (ws_size >= diag_need) {
        float* s1 = ws + FE_FLOATS;
        float* s2 = s1 + STREAM_FLOATS;
        float* s3 = s2 + STREAM_FLOATS;
        outer_write_v3<4><<<2048, 256, 0, stream>>>(proj, norms, out, s1, s2, s3);
    } else {
        outer_write_v3<1><<<2048, 256, 0, stream>>>(proj, norms, out, out, out, out);
    }
}

extern "C" void kernel_launch(void* const* d_in, const int* in_sizes, int n_in,
                              void* d_out, int out_size, void* d_ws, size_t ws_size,
                              hipStream_t stream)
{
    const float* x = (const float*)d_in[0];
    const float* y = (const float*)d_in[1];
    const float* W = (const float*)d_in[2];
    float* out = (float*)d_out;
    float* ws  = (float*)d_ws;

    const size_t need8 = ((size_t)8 * BROWS * DOUT + (size_t)BROWS * DOUT + 64) * sizeof(float);
    const size_t need4 = ((size_t)4 * BROWS * DOUT + (size_t)BROWS * DOUT + 64) * sizeof(float);

    if (ws_size >= need8)
        run_pipeline<8>(x, y, W, out, ws, ws_size, stream);
    else if (ws_size >= need4)
        run_pipeline<4>(x, y, W, out, ws, ws_size, stream);
    else
        run_pipeline<1>(x, y, W, out, ws, ws_size, stream);
}

// Round 7
// 107.996 us; speedup vs baseline: 3.6275x; 3.6275x over previous
//
#include <hip/hip_runtime.h>
#include <hip/hip_bf16.h>

// BilinearPooling: out[b, i*2048+j] = xp[b,i]*yp[b,j] / max(||xp_b||*||yp_b||, eps)
// where xp = x @ W^T, yp = y @ W^T.  B=32, D_IN=1024, D_OUT=2048, fp32.
// ||outer(u,v)||_F = ||u||*||v||  ->  never materialize z before normalizing.
//
// R6 diagnostic: writer = 5.6 TB/s (70% peak) vs fill = 6.7 TB/s (84%) at the
// SAME 2 GiB footprint; pattern-insensitive (3 patterns tied). Remaining
// difference vs fill: block geometry. Fill = one store per short-lived block
// (occupancy self-limits to ~10%, compact moving write window). R7: mimic
// fill exactly -- one dwordx4 store per thread, 131072 blocks, flat order.

#define BROWS 64       // stacked rows: 32 x-rows then 32 y-rows
#define DIN   1024
#define DOUT  2048
#define OTILE 64
#define LDA   132      // padded LDS leading dim (floats)
#define EPS_N 1e-12f

// ---------------- Kernel 1: partial GEMM  proj_partial[ks][r][o] ----------------
template <int KS>
__global__ __launch_bounds__(256) void gemm_partial_k(
    const float* __restrict__ x, const float* __restrict__ y,
    const float* __restrict__ W, float* __restrict__ part)
{
    constexpr int KCHUNK = DIN / KS;
    constexpr int NSTAGE = KCHUNK / 128;

    const int o0 = blockIdx.x * OTILE;
    const int ks = blockIdx.y;
    const int t  = threadIdx.x;

    __shared__ float As[BROWS * LDA];
    __shared__ float Bs[OTILE * LDA];

    const int tr = t >> 4;
    const int tc = t & 15;

    float acc[4][4];
#pragma unroll
    for (int a = 0; a < 4; ++a)
#pragma unroll
        for (int b = 0; b < 4; ++b) acc[a][b] = 0.f;

    for (int st = 0; st < NSTAGE; ++st) {
        const int k0 = ks * KCHUNK + st * 128;
        if (st) __syncthreads();
#pragma unroll
        for (int i = 0; i < 8; ++i) {
            int li = t + i * 256;
            int r  = li >> 5;
            int c4 = li & 31;
            const float* src =
                (r < 32 ? x + (size_t)r * DIN : y + (size_t)(r - 32) * DIN)
                + k0 + c4 * 4;
            *(float4*)&As[r * LDA + c4 * 4] = *(const float4*)src;
        }
#pragma unroll
        for (int i = 0; i < 8; ++i) {
            int li = t + i * 256;
            int r  = li >> 5;
            int c4 = li & 31;
            *(float4*)&Bs[r * LDA + c4 * 4] =
                *(const float4*)(W + (size_t)(o0 + r) * DIN + k0 + c4 * 4);
        }
        __syncthreads();

#pragma unroll 8
        for (int k4 = 0; k4 < 32; ++k4) {
            const int k = k4 * 4;
            float4 av[4], bv[4];
#pragma unroll
            for (int rr = 0; rr < 4; ++rr)
                av[rr] = *(float4*)&As[(tr + 16 * rr) * LDA + k];
#pragma unroll
            for (int cc = 0; cc < 4; ++cc)
                bv[cc] = *(float4*)&Bs[(tc + 16 * cc) * LDA + k];
#pragma unroll
            for (int rr = 0; rr < 4; ++rr)
#pragma unroll
                for (int cc = 0; cc < 4; ++cc) {
                    acc[rr][cc] = fmaf(av[rr].x, bv[cc].x, acc[rr][cc]);
                    acc[rr][cc] = fmaf(av[rr].y, bv[cc].y, acc[rr][cc]);
                    acc[rr][cc] = fmaf(av[rr].z, bv[cc].z, acc[rr][cc]);
                    acc[rr][cc] = fmaf(av[rr].w, bv[cc].w, acc[rr][cc]);
                }
        }
    }

#pragma unroll
    for (int rr = 0; rr < 4; ++rr) {
        const int r = tr + 16 * rr;
#pragma unroll
        for (int cc = 0; cc < 4; ++cc) {
            const int o = o0 + tc + 16 * cc;
            part[((size_t)(ks * BROWS + r)) * DOUT + o] = acc[rr][cc];
        }
    }
}

// ---------------- Kernel 2: reduce partials + row norms ----------------
template <int KS>
__global__ __launch_bounds__(256) void reduce_rows_k(
    const float* __restrict__ part, float* __restrict__ proj,
    float* __restrict__ norms)
{
    const int r = blockIdx.x;
    const int t = threadIdx.x;
    float ss = 0.f;
#pragma unroll
    for (int it = 0; it < 2; ++it) {
        const int j4 = t + it * 256;
        float4 s = make_float4(0.f, 0.f, 0.f, 0.f);
#pragma unroll
        for (int ks = 0; ks < KS; ++ks) {
            float4 v = *(const float4*)&part[((size_t)(ks * BROWS + r)) * DOUT + j4 * 4];
            s.x += v.x; s.y += v.y; s.z += v.z; s.w += v.w;
        }
        *(float4*)&proj[(size_t)r * DOUT + j4 * 4] = s;
        ss += s.x * s.x + s.y * s.y + s.z * s.z + s.w * s.w;
    }
#pragma unroll
    for (int m = 32; m >= 1; m >>= 1) ss += __shfl_xor(ss, m, 64);
    __shared__ float red[4];
    const int lane = t & 63, wv = t >> 6;
    if (lane == 0) red[wv] = ss;
    __syncthreads();
    if (t == 0) norms[r] = sqrtf(red[0] + red[1] + red[2] + red[3]);
}

// ---------------- Kernel 3: fill-mimic writer ----------------
// One dwordx4 store per thread, 131072 short-lived blocks, flat output order.
// g4 = bid*256 + t (float4 index). Row = 512 float4 -> j4 = g4 & 511;
// bi = g4 >> 9 gives b*2048 + i (pure SGPR: t only touches bits 0..7).
__global__ __launch_bounds__(256) void outer_write_fill(
    const float* __restrict__ proj, const float* __restrict__ norms,
    float* __restrict__ out)
{
    const int  t  = threadIdx.x;
    const unsigned g4 = (blockIdx.x << 8) + t;
    const int  j4 = g4 & 511;
    const unsigned bi = g4 >> 9;       // b*2048 + i  (block-uniform)
    const int  i  = bi & 2047;
    const int  b  = bi >> 11;

    const float s  = 1.0f / fmaxf(norms[b] * norms[32 + b], EPS_N);
    const float xv = proj[(size_t)b * DOUT + i] * s;
    const float4 yv = *(const float4*)&proj[(size_t)(32 + b) * DOUT + j4 * 4];

    ((float4*)out)[g4] = make_float4(xv * yv.x, xv * yv.y, xv * yv.z, xv * yv.w);
}

// ---------------- launch ----------------
template <int KS>
static void run_pipeline(const float* x, const float* y, const float* W,
                         float* out, float* ws, hipStream_t stream)
{
    float* part  = ws;
    float* proj  = part + (size_t)KS * BROWS * DOUT;
    float* norms = proj + (size_t)BROWS * DOUT;
    gemm_partial_k<KS><<<dim3(DOUT / OTILE, KS), 256, 0, stream>>>(x, y, W, part);
    reduce_rows_k<KS><<<BROWS, 256, 0, stream>>>(part, proj, norms);
    // 32*2048*2048 floats / 4 / 256 = 131072 blocks
    outer_write_fill<<<131072, 256, 0, stream>>>(proj, norms, out);
}

extern "C" void kernel_launch(void* const* d_in, const int* in_sizes, int n_in,
                              void* d_out, int out_size, void* d_ws, size_t ws_size,
                              hipStream_t stream)
{
    const float* x = (const float*)d_in[0];
    const float* y = (const float*)d_in[1];
    const float* W = (const float*)d_in[2];
    float* out = (float*)d_out;
    float* ws  = (float*)d_ws;

    const size_t need8 = ((size_t)8 * BROWS * DOUT + (size_t)BROWS * DOUT + 64) * sizeof(float);
    const size_t need4 = ((size_t)4 * BROWS * DOUT + (size_t)BROWS * DOUT + 64) * sizeof(float);

    if (ws_size >= need8)
        run_pipeline<8>(x, y, W, out, ws, stream);
    else if (ws_size >= need4)
        run_pipeline<4>(x, y, W, out, ws, stream);
    else
        run_pipeline<1>(x, y, W, out, ws, stream);
}

// Round 8
// 93.772 us; speedup vs baseline: 4.1777x; 1.1517x over previous
//
#include <hip/hip_runtime.h>
#include <hip/hip_bf16.h>

// BilinearPooling: out[b, i*2048+j] = xp[b,i]*yp[b,j] / max(||xp_b||*||yp_b||, eps)
// where xp = x @ W^T, yp = y @ W^T.  B=32, D_IN=1024, D_OUT=2048, fp32.
// ||outer(u,v)||_F = ||u||*||v||  ->  never materialize z before normalizing.
//
// R7: fill-mimic geometry (1 store/thread, 131072 short blocks, flat order)
// 110.6 -> 108.0 us; writer ~5.8 TB/s vs fill 6.7 TB/s on identical footprint.
// R8 single variable: nontemporal store (bypass L2 write-allocate) in the
// fill-mimic geometry. Pattern & occupancy already shown ~neutral.

#define BROWS 64       // stacked rows: 32 x-rows then 32 y-rows
#define DIN   1024
#define DOUT  2048
#define OTILE 64
#define LDA   132      // padded LDS leading dim (floats)
#define EPS_N 1e-12f

typedef float fx4 __attribute__((ext_vector_type(4)));  // native vec for NT stores

// ---------------- Kernel 1: partial GEMM  proj_partial[ks][r][o] ----------------
template <int KS>
__global__ __launch_bounds__(256) void gemm_partial_k(
    const float* __restrict__ x, const float* __restrict__ y,
    const float* __restrict__ W, float* __restrict__ part)
{
    constexpr int KCHUNK = DIN / KS;
    constexpr int NSTAGE = KCHUNK / 128;

    const int o0 = blockIdx.x * OTILE;
    const int ks = blockIdx.y;
    const int t  = threadIdx.x;

    __shared__ float As[BROWS * LDA];
    __shared__ float Bs[OTILE * LDA];

    const int tr = t >> 4;
    const int tc = t & 15;

    float acc[4][4];
#pragma unroll
    for (int a = 0; a < 4; ++a)
#pragma unroll
        for (int b = 0; b < 4; ++b) acc[a][b] = 0.f;

    for (int st = 0; st < NSTAGE; ++st) {
        const int k0 = ks * KCHUNK + st * 128;
        if (st) __syncthreads();
#pragma unroll
        for (int i = 0; i < 8; ++i) {
            int li = t + i * 256;
            int r  = li >> 5;
            int c4 = li & 31;
            const float* src =
                (r < 32 ? x + (size_t)r * DIN : y + (size_t)(r - 32) * DIN)
                + k0 + c4 * 4;
            *(float4*)&As[r * LDA + c4 * 4] = *(const float4*)src;
        }
#pragma unroll
        for (int i = 0; i < 8; ++i) {
            int li = t + i * 256;
            int r  = li >> 5;
            int c4 = li & 31;
            *(float4*)&Bs[r * LDA + c4 * 4] =
                *(const float4*)(W + (size_t)(o0 + r) * DIN + k0 + c4 * 4);
        }
        __syncthreads();

#pragma unroll 8
        for (int k4 = 0; k4 < 32; ++k4) {
            const int k = k4 * 4;
            float4 av[4], bv[4];
#pragma unroll
            for (int rr = 0; rr < 4; ++rr)
                av[rr] = *(float4*)&As[(tr + 16 * rr) * LDA + k];
#pragma unroll
            for (int cc = 0; cc < 4; ++cc)
                bv[cc] = *(float4*)&Bs[(tc + 16 * cc) * LDA + k];
#pragma unroll
            for (int rr = 0; rr < 4; ++rr)
#pragma unroll
                for (int cc = 0; cc < 4; ++cc) {
                    acc[rr][cc] = fmaf(av[rr].x, bv[cc].x, acc[rr][cc]);
                    acc[rr][cc] = fmaf(av[rr].y, bv[cc].y, acc[rr][cc]);
                    acc[rr][cc] = fmaf(av[rr].z, bv[cc].z, acc[rr][cc]);
                    acc[rr][cc] = fmaf(av[rr].w, bv[cc].w, acc[rr][cc]);
                }
        }
    }

#pragma unroll
    for (int rr = 0; rr < 4; ++rr) {
        const int r = tr + 16 * rr;
#pragma unroll
        for (int cc = 0; cc < 4; ++cc) {
            const int o = o0 + tc + 16 * cc;
            part[((size_t)(ks * BROWS + r)) * DOUT + o] = acc[rr][cc];
        }
    }
}

// ---------------- Kernel 2: reduce partials + row norms ----------------
template <int KS>
__global__ __launch_bounds__(256) void reduce_rows_k(
    const float* __restrict__ part, float* __restrict__ proj,
    float* __restrict__ norms)
{
    const int r = blockIdx.x;
    const int t = threadIdx.x;
    float ss = 0.f;
#pragma unroll
    for (int it = 0; it < 2; ++it) {
        const int j4 = t + it * 256;
        float4 s = make_float4(0.f, 0.f, 0.f, 0.f);
#pragma unroll
        for (int ks = 0; ks < KS; ++ks) {
            float4 v = *(const float4*)&part[((size_t)(ks * BROWS + r)) * DOUT + j4 * 4];
            s.x += v.x; s.y += v.y; s.z += v.z; s.w += v.w;
        }
        *(float4*)&proj[(size_t)r * DOUT + j4 * 4] = s;
        ss += s.x * s.x + s.y * s.y + s.z * s.z + s.w * s.w;
    }
#pragma unroll
    for (int m = 32; m >= 1; m >>= 1) ss += __shfl_xor(ss, m, 64);
    __shared__ float red[4];
    const int lane = t & 63, wv = t >> 6;
    if (lane == 0) red[wv] = ss;
    __syncthreads();
    if (t == 0) norms[r] = sqrtf(red[0] + red[1] + red[2] + red[3]);
}

// ---------------- Kernel 3: fill-mimic writer + nontemporal store ----------------
// One dwordx4 NT store per thread, 131072 short-lived blocks, flat output order.
__global__ __launch_bounds__(256) void outer_write_fill_nt(
    const float* __restrict__ proj, const float* __restrict__ norms,
    float* __restrict__ out)
{
    const int  t  = threadIdx.x;
    const unsigned g4 = (blockIdx.x << 8) + t;
    const int  j4 = g4 & 511;
    const unsigned bi = g4 >> 9;       // b*2048 + i  (block-uniform)
    const int  i  = bi & 2047;
    const int  b  = bi >> 11;

    const float s  = 1.0f / fmaxf(norms[b] * norms[32 + b], EPS_N);
    const float xv = proj[(size_t)b * DOUT + i] * s;
    const float4 yv = *(const float4*)&proj[(size_t)(32 + b) * DOUT + j4 * 4];

    fx4 o = { xv * yv.x, xv * yv.y, xv * yv.z, xv * yv.w };
    __builtin_nontemporal_store(o, (fx4*)out + g4);
}

// ---------------- launch ----------------
template <int KS>
static void run_pipeline(const float* x, const float* y, const float* W,
                         float* out, float* ws, hipStream_t stream)
{
    float* part  = ws;
    float* proj  = part + (size_t)KS * BROWS * DOUT;
    float* norms = proj + (size_t)BROWS * DOUT;
    gemm_partial_k<KS><<<dim3(DOUT / OTILE, KS), 256, 0, stream>>>(x, y, W, part);
    reduce_rows_k<KS><<<BROWS, 256, 0, stream>>>(part, proj, norms);
    outer_write_fill_nt<<<131072, 256, 0, stream>>>(proj, norms, out);
}

extern "C" void kernel_launch(void* const* d_in, const int* in_sizes, int n_in,
                              void* d_out, int out_size, void* d_ws, size_t ws_size,
                              hipStream_t stream)
{
    const float* x = (const float*)d_in[0];
    const float* y = (const float*)d_in[1];
    const float* W = (const float*)d_in[2];
    float* out = (float*)d_out;
    float* ws  = (float*)d_ws;

    const size_t need8 = ((size_t)8 * BROWS * DOUT + (size_t)BROWS * DOUT + 64) * sizeof(float);
    const size_t need4 = ((size_t)4 * BROWS * DOUT + (size_t)BROWS * DOUT + 64) * sizeof(float);

    if (ws_size >= need8)
        run_pipeline<8>(x, y, W, out, ws, stream);
    else if (ws_size >= need4)
        run_pipeline<4>(x, y, W, out, ws, stream);
    else
        run_pipeline<1>(x, y, W, out, ws, stream);
}